// Round 3
// baseline (990.828 us; speedup 1.0000x reference)
//
#include <hip/hip_runtime.h>
#include <stdint.h>

// ---------------------------------------------------------------------------
// SpikeMLP (all fp32 I/O):
//   h = x @ w1^T            (16384,512)x(2048,512)^T -> (16384,2048)
//   spikes,rate = LIF(h)    scan over t (4 steps, rows grouped (b,t,s))
//   out = spikes @ w2^T     (16384,2048)x(512,2048)^T -> (16384,512)
// d_out: 8388608 fp32 out elems + 1 fp32 rate.
// Workspace: [0,256): u32 spike counter; [256,...): spikes as bf16 (67 MB).
//
// Numerics: the np reference runs in float32. To match its discontinuous
// spike decisions (v > 1) we replicate f32 arithmetic exactly:
//   - h: per-element k-sequential f32 FMA over k=0..511 (BLAS micro-kernel
//     order). Accumulators carried across k-chunks in registers.
//   - LIF: v = f32(beta*v) then f32(v+h)  (two roundings, NO fma), beta=0.95f,
//     spike iff v > 1.0f, hard reset via select.
// GEMM2 is continuous in its inputs (spikes are exactly {0,1}) -> any f32
// order is far within the 2% threshold.
// ---------------------------------------------------------------------------

#define KT  16
#define PAD 68   // floats per LDS k-row: 64 + 4 keeps float4 alignment

__device__ __forceinline__ float bf2f(unsigned short u) {
  union { unsigned u; float f; } un; un.u = ((unsigned)u) << 16; return un.f;
}

// ---------------------------------------------------------------------------
// K1: fused GEMM1 (f32 seq-FMA) + LIF. Tile 64(bs) x 64(hidden), 256 threads,
// 4x4 outputs/thread. Grid (64, 32). Membrane v kept in registers across t.
// ---------------------------------------------------------------------------
__global__ __launch_bounds__(256) void k1_gemm_lif(
    const float* __restrict__ x,          // (16384, 512), row=((b*4+t)*256+s)
    const float* __restrict__ w1,         // (2048, 512)
    unsigned short* __restrict__ spikes,  // (16384, 2048) bf16 {0,1}
    unsigned* __restrict__ cnt_out)
{
  __shared__ float sA[KT][PAD];
  __shared__ float sB[KT][PAD];

  const int tid = threadIdx.x;
  const int tx  = tid & 15;      // output col group (4 cols)
  const int ty  = tid >> 4;      // output row group (4 rows)
  const int lr  = tid >> 2;      // staging row 0..63
  const int lg  = tid & 3;       // staging k-group 0..3

  const int bs0 = blockIdx.x * 64;   // (b*256+s) tile base; one b per tile
  const int h0  = blockIdx.y * 64;
  const int b   = bs0 >> 8;
  const int s0  = bs0 & 255;

  float v[4][4];
#pragma unroll
  for (int i = 0; i < 4; ++i)
#pragma unroll
    for (int j = 0; j < 4; ++j) v[i][j] = 0.0f;

  unsigned cnt = 0;

  for (int t = 0; t < 4; ++t) {
    const size_t arow0 = ((size_t)(b * 4 + t)) * 256 + s0;

    float acc[4][4];
#pragma unroll
    for (int i = 0; i < 4; ++i)
#pragma unroll
      for (int j = 0; j < 4; ++j) acc[i][j] = 0.0f;

    for (int k0 = 0; k0 < 512; k0 += KT) {
      __syncthreads();  // protect LDS from previous chunk's readers
      float4 av = *(const float4*)&x [(arow0 + lr) * 512 + k0 + lg * 4];
      float4 bv = *(const float4*)&w1[(size_t)(h0 + lr) * 512 + k0 + lg * 4];
      sA[lg * 4 + 0][lr] = av.x; sA[lg * 4 + 1][lr] = av.y;
      sA[lg * 4 + 2][lr] = av.z; sA[lg * 4 + 3][lr] = av.w;
      sB[lg * 4 + 0][lr] = bv.x; sB[lg * 4 + 1][lr] = bv.y;
      sB[lg * 4 + 2][lr] = bv.z; sB[lg * 4 + 3][lr] = bv.w;
      __syncthreads();

#pragma unroll
      for (int k = 0; k < KT; ++k) {
        float4 a4 = *(const float4*)&sA[k][ty * 4];
        float4 b4 = *(const float4*)&sB[k][tx * 4];
        float aa[4] = {a4.x, a4.y, a4.z, a4.w};
        float bb[4] = {b4.x, b4.y, b4.z, b4.w};
#pragma unroll
        for (int i = 0; i < 4; ++i)
#pragma unroll
          for (int j = 0; j < 4; ++j)
            acc[i][j] = __builtin_fmaf(aa[i], bb[j], acc[i][j]);
      }
    }

    // LIF step (f32, numpy op-for-op): v = f32(0.95*v) + h; spk = v > 1; reset
#pragma unroll
    for (int i = 0; i < 4; ++i) {
      unsigned short sp4[4];
#pragma unroll
      for (int j = 0; j < 4; ++j) {
        float vv = __fmul_rn(0.95f, v[i][j]);   // separate rounding, no fma
        vv = __fadd_rn(vv, acc[i][j]);
        bool s = vv > 1.0f;
        cnt += s ? 1u : 0u;
        v[i][j] = s ? 0.0f : vv;
        sp4[j] = s ? (unsigned short)0x3F80 : (unsigned short)0;
      }
      *(ushort4*)&spikes[(arow0 + ty * 4 + i) * 2048 + h0 + tx * 4] =
          *(const ushort4*)sp4;
    }
  }

  // wave-reduce spike count -> one atomic per wave
#pragma unroll
  for (int off = 32; off; off >>= 1) cnt += __shfl_down(cnt, off);
  if ((tid & 63) == 0) atomicAdd(cnt_out, cnt);
}

// ---------------------------------------------------------------------------
// K2: out = spikes @ w2^T, fp32 FMA. Tile 64x64, 4x4/thread. Grid (256, 8).
// ---------------------------------------------------------------------------
__global__ __launch_bounds__(256) void k2_gemm(
    const unsigned short* __restrict__ spikes,  // (16384, 2048) bf16 {0,1}
    const float* __restrict__ w2,               // (512, 2048)
    float* __restrict__ out)                    // (16384, 512)
{
  __shared__ float sA[KT][PAD];
  __shared__ float sB[KT][PAD];

  const int tid = threadIdx.x;
  const int tx  = tid & 15;
  const int ty  = tid >> 4;
  const int lr  = tid >> 2;
  const int lg  = tid & 3;

  const size_t r0 = (size_t)blockIdx.x * 64;
  const int    d0 = blockIdx.y * 64;

  float acc[4][4];
#pragma unroll
  for (int i = 0; i < 4; ++i)
#pragma unroll
    for (int j = 0; j < 4; ++j) acc[i][j] = 0.0f;

  for (int k0 = 0; k0 < 2048; k0 += KT) {
    __syncthreads();
    ushort4 av = *(const ushort4*)&spikes[(r0 + lr) * 2048 + k0 + lg * 4];
    float4  bv = *(const float4*)&w2[(size_t)(d0 + lr) * 2048 + k0 + lg * 4];
    sA[lg * 4 + 0][lr] = bf2f(av.x); sA[lg * 4 + 1][lr] = bf2f(av.y);
    sA[lg * 4 + 2][lr] = bf2f(av.z); sA[lg * 4 + 3][lr] = bf2f(av.w);
    sB[lg * 4 + 0][lr] = bv.x; sB[lg * 4 + 1][lr] = bv.y;
    sB[lg * 4 + 2][lr] = bv.z; sB[lg * 4 + 3][lr] = bv.w;
    __syncthreads();

#pragma unroll
    for (int k = 0; k < KT; ++k) {
      float4 a4 = *(const float4*)&sA[k][ty * 4];
      float4 b4 = *(const float4*)&sB[k][tx * 4];
      float aa[4] = {a4.x, a4.y, a4.z, a4.w};
      float bb[4] = {b4.x, b4.y, b4.z, b4.w};
#pragma unroll
      for (int i = 0; i < 4; ++i)
#pragma unroll
        for (int j = 0; j < 4; ++j)
          acc[i][j] = __builtin_fmaf(aa[i], bb[j], acc[i][j]);
    }
  }

#pragma unroll
  for (int i = 0; i < 4; ++i) {
    float4 o = make_float4(acc[i][0], acc[i][1], acc[i][2], acc[i][3]);
    *(float4*)&out[(r0 + ty * 4 + i) * 512 + d0 + tx * 4] = o;
  }
}

// ---------------------------------------------------------------------------
// K3: rate = count / 33554432 -> fp32 at d_out[8388608]
// ---------------------------------------------------------------------------
__global__ void k3_rate(const unsigned* __restrict__ cnt, float* __restrict__ dst) {
  dst[0] = (float)((double)(*cnt) / 33554432.0);
}

extern "C" void kernel_launch(void* const* d_in, const int* in_sizes, int n_in,
                              void* d_out, int out_size, void* d_ws, size_t ws_size,
                              hipStream_t stream) {
  const float* x  = (const float*)d_in[0];
  const float* w1 = (const float*)d_in[1];
  const float* w2 = (const float*)d_in[2];
  float* out = (float*)d_out;

  unsigned* cnt = (unsigned*)d_ws;
  unsigned short* spikes = (unsigned short*)((char*)d_ws + 256);

  hipMemsetAsync(d_ws, 0, 256, stream);  // zero the spike counter

  hipLaunchKernelGGL(k1_gemm_lif, dim3(64, 32), dim3(256), 0, stream,
                     x, w1, spikes, cnt);
  hipLaunchKernelGGL(k2_gemm, dim3(256, 8), dim3(256), 0, stream,
                     spikes, w2, out);
  hipLaunchKernelGGL(k3_rate, dim3(1), dim3(1), 0, stream, cnt, out + 8388608);
}

// Round 5
// 604.590 us; speedup vs baseline: 1.6388x; 1.6388x over previous
//
#include <hip/hip_runtime.h>
#include <stdint.h>

// ---------------------------------------------------------------------------
// SpikeMLP (all fp32 I/O):
//   h = x @ w1^T            (16384,512)x(2048,512)^T -> (16384,2048)
//   spikes,rate = LIF(h)    scan over t (4 steps, rows grouped (b,t,s))
//   out = spikes @ w2^T     (16384,2048)x(512,2048)^T -> (16384,512)
//
// Numerics contract (established round 3, DO NOT BREAK):
//   - GEMM1 (k1): per-element f32 sequential FMA over k=0..511 ascending,
//     one accumulator -> bit-exact match of the np reference's h.
//   - LIF: vv = __fmul_rn(0.95f, v); vv = __fadd_rn(vv, h); spike = vv > 1.
//   - GEMM2 is continuous in spikes {0,1} -> MFMA allowed. w2 split into
//     bf16 hi+lo (residual ~2^-18 relative) keeps error at round-3 level.
//
// Workspace layout:
//   [0,256)                u32 spike counter
//   [256, 256+67108864)    spikes bf16 (16384 x 2048)
//   then w2_hi bf16 (512x2048, 2 MB), w2_lo bf16 (2 MB)  [only if ws fits]
// ---------------------------------------------------------------------------

typedef __attribute__((ext_vector_type(8))) short short8;   // 8 bf16 = 16 B
typedef __attribute__((ext_vector_type(4))) float f32x4;

#define AS1 __attribute__((address_space(1)))
#define AS3 __attribute__((address_space(3)))

__device__ __forceinline__ void load_lds16(const void* g, void* l) {
  __builtin_amdgcn_global_load_lds((const AS1 void*)g, (AS3 void*)l, 16, 0, 0);
}

__device__ __forceinline__ unsigned short f2bf(float f) {
  union { float f; unsigned u; } un; un.f = f;
  unsigned r = un.u + 0x7FFF + ((un.u >> 16) & 1);   // RNE
  return (unsigned short)(r >> 16);
}
__device__ __forceinline__ float bf2f(unsigned short u) {
  union { unsigned u; float f; } un; un.u = ((unsigned)u) << 16; return un.f;
}

// ---------------------------------------------------------------------------
// K0: split w2 (fp32) into bf16 hi + lo.  n = 512*2048 = 1048576, x4/thread.
// ---------------------------------------------------------------------------
__global__ __launch_bounds__(256) void k0_split(
    const float* __restrict__ w2, unsigned short* __restrict__ hi,
    unsigned short* __restrict__ lo)
{
  int i = (blockIdx.x * 256 + threadIdx.x) * 4;
  float4 w = *(const float4*)&w2[i];
  unsigned short h4[4], l4[4];
  float ws[4] = {w.x, w.y, w.z, w.w};
#pragma unroll
  for (int c = 0; c < 4; ++c) {
    unsigned short h = f2bf(ws[c]);
    h4[c] = h;
    l4[c] = f2bf(ws[c] - bf2f(h));
  }
  *(ushort4*)&hi[i] = *(const ushort4*)h4;
  *(ushort4*)&lo[i] = *(const ushort4*)l4;
}

// ---------------------------------------------------------------------------
// K1: fused GEMM1 (f32 seq-FMA, bit-exact) + LIF.
// Tile 64(bs-rows) x 128(hidden-cols), 256 threads, 4x8 per thread.
// Grid (64, 16)  <-- 4096/64 x 2048/128. KT=32. v in registers across t.
// ---------------------------------------------------------------------------
#define K1KT 32
#define PA 68
#define PB 132

__global__ __launch_bounds__(256) void k1_gemm_lif(
    const float* __restrict__ x,          // (16384, 512), row=((b*4+t)*256+s)
    const float* __restrict__ w1,         // (2048, 512)
    unsigned short* __restrict__ spikes,  // (16384, 2048) bf16 {0,1}
    unsigned* __restrict__ cnt_out)
{
  __shared__ float sA[K1KT][PA];   // A: [k][row 0..63]   8704 B
  __shared__ float sB[K1KT][PB];   // B: [k][col 0..127] 16896 B

  const int tid = threadIdx.x;
  const int tx  = tid & 15;       // col group
  const int ty  = tid >> 4;       // row group: rows ty*4..+3

  const int bs0 = blockIdx.x * 64;    // (b*256+s) tile base, 0..4032
  const int h0  = blockIdx.y * 128;   // 0..1920
  const int b   = bs0 >> 8;
  const int s0  = bs0 & 255;

  const int ar0 = tid >> 3;            // staging row base (0..31)
  const int akc = (tid & 7) * 4;       // staging k-offset

  float v[4][8];
#pragma unroll
  for (int i = 0; i < 4; ++i)
#pragma unroll
    for (int j = 0; j < 8; ++j) v[i][j] = 0.0f;

  unsigned cnt = 0;

  for (int t = 0; t < 4; ++t) {
    const size_t arow0 = ((size_t)(b * 4 + t)) * 256 + s0;

    float acc[4][8];
#pragma unroll
    for (int i = 0; i < 4; ++i)
#pragma unroll
      for (int j = 0; j < 8; ++j) acc[i][j] = 0.0f;

    for (int k0 = 0; k0 < 512; k0 += K1KT) {
      __syncthreads();  // protect LDS from previous chunk's readers
      // stage A: 64 rows x 32 k = 512 float4, 2 per thread
#pragma unroll
      for (int j = 0; j < 2; ++j) {
        int r = ar0 + j * 32;
        float4 a = *(const float4*)&x[(arow0 + r) * 512 + k0 + akc];
        sA[akc + 0][r] = a.x; sA[akc + 1][r] = a.y;
        sA[akc + 2][r] = a.z; sA[akc + 3][r] = a.w;
      }
      // stage B: 128 cols x 32 k = 1024 float4, 4 per thread
#pragma unroll
      for (int j = 0; j < 4; ++j) {
        int r = ar0 + j * 32;
        float4 wv = *(const float4*)&w1[(size_t)(h0 + r) * 512 + k0 + akc];
        sB[akc + 0][r] = wv.x; sB[akc + 1][r] = wv.y;
        sB[akc + 2][r] = wv.z; sB[akc + 3][r] = wv.w;
      }
      __syncthreads();

#pragma unroll
      for (int k = 0; k < K1KT; ++k) {
        float4 a4  = *(const float4*)&sA[k][ty * 4];        // broadcast
        float4 b4a = *(const float4*)&sB[k][tx * 4];        // 2-way, free
        float4 b4b = *(const float4*)&sB[k][64 + tx * 4];   // 2-way, free
        float aa[4] = {a4.x, a4.y, a4.z, a4.w};
        float ba[4] = {b4a.x, b4a.y, b4a.z, b4a.w};
        float bb[4] = {b4b.x, b4b.y, b4b.z, b4b.w};
#pragma unroll
        for (int i = 0; i < 4; ++i) {
#pragma unroll
          for (int j = 0; j < 4; ++j)
            acc[i][j] = __builtin_fmaf(aa[i], ba[j], acc[i][j]);
#pragma unroll
          for (int j = 0; j < 4; ++j)
            acc[i][4 + j] = __builtin_fmaf(aa[i], bb[j], acc[i][4 + j]);
        }
      }
    }

    // LIF step (f32, numpy op-for-op): v = f32(0.95*v) + h; spk = v>1; reset
#pragma unroll
    for (int i = 0; i < 4; ++i) {
      unsigned short sp[8];
#pragma unroll
      for (int j = 0; j < 8; ++j) {
        float vv = __fmul_rn(0.95f, v[i][j]);   // separate rounding, no fma
        vv = __fadd_rn(vv, acc[i][j]);
        bool s = vv > 1.0f;
        cnt += s ? 1u : 0u;
        v[i][j] = s ? 0.0f : vv;
        sp[j] = s ? (unsigned short)0x3F80 : (unsigned short)0;
      }
      unsigned short* row = spikes + (arow0 + ty * 4 + i) * 2048 + h0;
      *(ushort4*)&row[tx * 4]      = *(const ushort4*)&sp[0];
      *(ushort4*)&row[64 + tx * 4] = *(const ushort4*)&sp[4];
    }
  }

  // wave-reduce spike count -> one atomic per wave
#pragma unroll
  for (int off = 32; off; off >>= 1) cnt += __shfl_down(cnt, off);
  if ((tid & 63) == 0) atomicAdd(cnt_out, cnt);
}

// ---------------------------------------------------------------------------
// K2: out = spikes @ (w2_hi + w2_lo)^T via bf16 MFMA, fp32 accum.
// 128x128 tile, BK=64, global_load_lds w=16, XOR swizzle. Grid (128, 4).
// ---------------------------------------------------------------------------
__global__ __launch_bounds__(256) void k2_gemm_mfma(
    const unsigned short* __restrict__ spikes,  // (16384, 2048) bf16
    const unsigned short* __restrict__ w2h,     // (512, 2048) bf16
    const unsigned short* __restrict__ w2l,     // (512, 2048) bf16
    float* __restrict__ out)                    // (16384, 512) fp32
{
  __shared__ alignas(16) short smA [128 * 64];
  __shared__ alignas(16) short smBh[128 * 64];
  __shared__ alignas(16) short smBl[128 * 64];

  const int tid  = threadIdx.x;
  const int lane = tid & 63;
  const int quad = lane >> 4;
  const int l15  = lane & 15;
  const int wv   = tid >> 6;
  const int wm   = wv & 1;
  const int wn   = wv >> 1;

  const size_t r0 = (size_t)blockIdx.x * 128;   // 0..16256
  const int    d0 = blockIdx.y * 128;           // 0..384

  int srow[4], sg8[4];
#pragma unroll
  for (int j = 0; j < 4; ++j) {
    int gi  = j * 256 + tid;
    srow[j] = gi >> 3;
    sg8[j]  = ((gi & 7) ^ (srow[j] & 7)) * 8;
  }

  const unsigned short* ab  = spikes + r0 * 2048;
  const unsigned short* bhb = w2h + (size_t)d0 * 2048;
  const unsigned short* blb = w2l + (size_t)d0 * 2048;

  f32x4 acc[4][4] = {};

  for (int k0 = 0; k0 < 2048; k0 += 64) {
    __syncthreads();
#pragma unroll
    for (int j = 0; j < 4; ++j) {
      load_lds16(ab  + (size_t)srow[j] * 2048 + k0 + sg8[j],
                 &smA [(j * 256 + tid) * 8]);
      load_lds16(bhb + (size_t)srow[j] * 2048 + k0 + sg8[j],
                 &smBh[(j * 256 + tid) * 8]);
      load_lds16(blb + (size_t)srow[j] * 2048 + k0 + sg8[j],
                 &smBl[(j * 256 + tid) * 8]);
    }
    __syncthreads();

#pragma unroll
    for (int ks = 0; ks < 2; ++ks) {
      short8 af[4], bh[4], bl[4];
#pragma unroll
      for (int mi = 0; mi < 4; ++mi) {
        int m = wm * 64 + mi * 16 + l15;
        af[mi] = ((const short8*)smA)[m * 8 + ((ks * 4 + quad) ^ (m & 7))];
      }
#pragma unroll
      for (int ni = 0; ni < 4; ++ni) {
        int n = wn * 64 + ni * 16 + l15;
        int sl = n * 8 + ((ks * 4 + quad) ^ (n & 7));
        bh[ni] = ((const short8*)smBh)[sl];
        bl[ni] = ((const short8*)smBl)[sl];
      }
#pragma unroll
      for (int mi = 0; mi < 4; ++mi)
#pragma unroll
        for (int ni = 0; ni < 4; ++ni) {
          acc[mi][ni] = __builtin_amdgcn_mfma_f32_16x16x32_bf16(
              af[mi], bh[ni], acc[mi][ni], 0, 0, 0);
          acc[mi][ni] = __builtin_amdgcn_mfma_f32_16x16x32_bf16(
              af[mi], bl[ni], acc[mi][ni], 0, 0, 0);
        }
    }
  }

  float* ob = out + r0 * 512 + d0;
#pragma unroll
  for (int mi = 0; mi < 4; ++mi)
#pragma unroll
    for (int ni = 0; ni < 4; ++ni)
#pragma unroll
      for (int r = 0; r < 4; ++r) {
        int rr = wm * 64 + mi * 16 + quad * 4 + r;   // C/D: row=quad*4+reg
        int cc = wn * 64 + ni * 16 + l15;            //      col=lane&15
        ob[(size_t)rr * 512 + cc] = acc[mi][ni][r];
      }
}

// ---------------------------------------------------------------------------
// K2 fallback (no extra ws): out = spikes @ w2^T, fp32 VALU. Grid (256, 8).
// ---------------------------------------------------------------------------
#define KT 16
#define PADF 68

__global__ __launch_bounds__(256) void k2_gemm_valu(
    const unsigned short* __restrict__ spikes,  // (16384, 2048) bf16 {0,1}
    const float* __restrict__ w2,               // (512, 2048)
    float* __restrict__ out)                    // (16384, 512)
{
  __shared__ float sA[KT][PADF];
  __shared__ float sB[KT][PADF];

  const int tid = threadIdx.x;
  const int tx  = tid & 15;
  const int ty  = tid >> 4;
  const int lr  = tid >> 2;
  const int lg  = tid & 3;

  const size_t r0 = (size_t)blockIdx.x * 64;
  const int    d0 = blockIdx.y * 64;

  float acc[4][4];
#pragma unroll
  for (int i = 0; i < 4; ++i)
#pragma unroll
    for (int j = 0; j < 4; ++j) acc[i][j] = 0.0f;

  for (int k0 = 0; k0 < 2048; k0 += KT) {
    __syncthreads();
    ushort4 av = *(const ushort4*)&spikes[(r0 + lr) * 2048 + k0 + lg * 4];
    float4  bv = *(const float4*)&w2[(size_t)(d0 + lr) * 2048 + k0 + lg * 4];
    sA[lg * 4 + 0][lr] = bf2f(av.x); sA[lg * 4 + 1][lr] = bf2f(av.y);
    sA[lg * 4 + 2][lr] = bf2f(av.z); sA[lg * 4 + 3][lr] = bf2f(av.w);
    sB[lg * 4 + 0][lr] = bv.x; sB[lg * 4 + 1][lr] = bv.y;
    sB[lg * 4 + 2][lr] = bv.z; sB[lg * 4 + 3][lr] = bv.w;
    __syncthreads();

#pragma unroll
    for (int k = 0; k < KT; ++k) {
      float4 a4 = *(const float4*)&sA[k][ty * 4];
      float4 b4 = *(const float4*)&sB[k][tx * 4];
      float aa[4] = {a4.x, a4.y, a4.z, a4.w};
      float bb[4] = {b4.x, b4.y, b4.z, b4.w};
#pragma unroll
      for (int i = 0; i < 4; ++i)
#pragma unroll
        for (int j = 0; j < 4; ++j)
          acc[i][j] = __builtin_fmaf(aa[i], bb[j], acc[i][j]);
    }
  }

#pragma unroll
  for (int i = 0; i < 4; ++i) {
    float4 o = make_float4(acc[i][0], acc[i][1], acc[i][2], acc[i][3]);
    *(float4*)&out[(r0 + ty * 4 + i) * 512 + d0 + tx * 4] = o;
  }
}

// ---------------------------------------------------------------------------
// K3: rate = count / 33554432 -> fp32 at d_out[8388608]
// ---------------------------------------------------------------------------
__global__ void k3_rate(const unsigned* __restrict__ cnt, float* __restrict__ dst) {
  dst[0] = (float)((double)(*cnt) / 33554432.0);
}

extern "C" void kernel_launch(void* const* d_in, const int* in_sizes, int n_in,
                              void* d_out, int out_size, void* d_ws, size_t ws_size,
                              hipStream_t stream) {
  const float* x  = (const float*)d_in[0];
  const float* w1 = (const float*)d_in[1];
  const float* w2 = (const float*)d_in[2];
  float* out = (float*)d_out;

  unsigned* cnt = (unsigned*)d_ws;
  unsigned short* spikes = (unsigned short*)((char*)d_ws + 256);
  const size_t SPIKES_B = (size_t)16384 * 2048 * 2;           // 67108864
  unsigned short* w2h = (unsigned short*)((char*)d_ws + 256 + SPIKES_B);
  unsigned short* w2l = w2h + (size_t)512 * 2048;
  const size_t NEED_SPLIT = 256 + SPIKES_B + 2 * (size_t)512 * 2048 * 2;

  hipMemsetAsync(d_ws, 0, 256, stream);  // zero the spike counter

  hipLaunchKernelGGL(k1_gemm_lif, dim3(64, 16), dim3(256), 0, stream,
                     x, w1, spikes, cnt);

  if (ws_size >= NEED_SPLIT) {
    hipLaunchKernelGGL(k0_split, dim3(1024), dim3(256), 0, stream, w2, w2h, w2l);
    hipLaunchKernelGGL(k2_gemm_mfma, dim3(128, 4), dim3(256), 0, stream,
                       spikes, w2h, w2l, out);
  } else {
    hipLaunchKernelGGL(k2_gemm_valu, dim3(256, 8), dim3(256), 0, stream,
                       spikes, w2, out);
  }

  hipLaunchKernelGGL(k3_rate, dim3(1), dim3(1), 0, stream, cnt, out + 8388608);
}

// Round 7
// 562.584 us; speedup vs baseline: 1.7612x; 1.0747x over previous
//
#include <hip/hip_runtime.h>
#include <stdint.h>

// ---------------------------------------------------------------------------
// SpikeMLP (all fp32 I/O):
//   h = x @ w1^T            (16384,512)x(2048,512)^T -> (16384,2048)
//   spikes,rate = LIF(h)    scan over t (4 steps, rows grouped (b,t,s))
//   out = spikes @ w2^T     (16384,2048)x(512,2048)^T -> (16384,512)
//
// Numerics contract (established round 3, DO NOT BREAK):
//   - GEMM1 (k1): per-element f32 sequential FMA over k=0..511 ascending,
//     one accumulator -> bit-exact match of the np reference's h.
//   - LIF: vv = __fmul_rn(0.95f, v); vv = __fadd_rn(vv, h); spike = vv > 1.
//   - GEMM2 is continuous in spikes {0,1} -> MFMA allowed (w2 hi+lo bf16).
//
// k1 (round 7): 256x128 tile (rows = 4t x 64s), one K=512 pass, 16x8 micro
// (6 ds_read_b128 per 128 FMAs). LIF t-chain via __shfl (t-owners of one
// (s,col) sit at lanes t*16+tx of the same wave). LDS XOR swizzle on
// power-of-2 groups ONLY (round 6 bug: 68-stride groups overflowed):
//   sA slot = r ^ 4*(kg ^ (r>>6)), r in [0,256), SA_STR=256
//   sB slot = c ^ 4*kg,            c in [0,128), SB_STR=128
// XOR touches bits 2..4 < group alignment 64 -> closed + bijective.
// ---------------------------------------------------------------------------

typedef __attribute__((ext_vector_type(8))) short short8;   // 8 bf16 = 16 B
typedef __attribute__((ext_vector_type(4))) float f32x4;

#define AS1 __attribute__((address_space(1)))
#define AS3 __attribute__((address_space(3)))

__device__ __forceinline__ void load_lds16(const void* g, void* l) {
  __builtin_amdgcn_global_load_lds((const AS1 void*)g, (AS3 void*)l, 16, 0, 0);
}

__device__ __forceinline__ unsigned short f2bf(float f) {
  union { float f; unsigned u; } un; un.f = f;
  unsigned r = un.u + 0x7FFF + ((un.u >> 16) & 1);   // RNE
  return (unsigned short)(r >> 16);
}
__device__ __forceinline__ float bf2f(unsigned short u) {
  union { unsigned u; float f; } un; un.u = ((unsigned)u) << 16; return un.f;
}

// ---------------------------------------------------------------------------
// K0: split w2 (fp32) into bf16 hi + lo.
// ---------------------------------------------------------------------------
__global__ __launch_bounds__(256) void k0_split(
    const float* __restrict__ w2, unsigned short* __restrict__ hi,
    unsigned short* __restrict__ lo)
{
  int i = (blockIdx.x * 256 + threadIdx.x) * 4;
  float4 w = *(const float4*)&w2[i];
  unsigned short h4[4], l4[4];
  float ws[4] = {w.x, w.y, w.z, w.w};
#pragma unroll
  for (int c = 0; c < 4; ++c) {
    unsigned short h = f2bf(ws[c]);
    h4[c] = h;
    l4[c] = f2bf(ws[c] - bf2f(h));
  }
  *(ushort4*)&hi[i] = *(const ushort4*)h4;
  *(ushort4*)&lo[i] = *(const ushort4*)l4;
}

// ---------------------------------------------------------------------------
// K1: fused GEMM1 (f32 seq-FMA, bit-exact) + LIF via shfl epilogue.
// Block tile: 256 rows (4t x 64s) x 128 cols. 256 threads, 16x8 micro.
// Grid (64, 16): bx -> (b = bx>>2, s0 = (bx&3)*64); by -> h0 = by*128.
// ---------------------------------------------------------------------------
#define K1KT 32
#define SA_STR 256
#define SB_STR 128

__global__ __launch_bounds__(256, 2) void k1_gemm_lif(
    const float* __restrict__ x,          // (16384, 512), row=((b*4+t)*256+s)
    const float* __restrict__ w1,         // (2048, 512)
    unsigned short* __restrict__ spikes,  // (16384, 2048) bf16 {0,1}
    unsigned* __restrict__ cnt_out)
{
  __shared__ float sA[K1KT * SA_STR];   // 32 KB
  __shared__ float sB[K1KT * SB_STR];   // 16 KB

  const int tid = threadIdx.x;
  const int tx  = tid & 15;
  const int ty  = tid >> 4;
  const int t   = ty & 3;     // this thread's time step
  const int ssg = ty >> 2;    // s-subgroup (== wave id)

  const int bx = blockIdx.x;
  const int b  = bx >> 2;
  const int s0 = (bx & 3) * 64;
  const int h0 = blockIdx.y * 128;

  const int u  = tid >> 3;    // staging row base 0..31
  const int kg = tid & 7;     // staging k-group 0..7

  float acc[16][8];
#pragma unroll
  for (int i = 0; i < 16; ++i)
#pragma unroll
    for (int j = 0; j < 8; ++j) acc[i][j] = 0.0f;

  const int aBase  = t * 64 + ssg * 16;   // slot base (pre-XOR)
  const int tXor   = 4 * t;               // de-alias the 4 t-subtiles
  const int bBase0 = tx * 4;
  const int bBase1 = 64 + tx * 4;

  for (int k0 = 0; k0 < 512; k0 += K1KT) {
    __syncthreads();  // protect LDS from previous chunk's readers

    // stage A: 256 rows x 32 k; thread: rows u+32j, k-cols kg*4..+3
#pragma unroll
    for (int j = 0; j < 8; ++j) {
      int r  = u + 32 * j;
      int tr = r >> 6, ss = r & 63;
      size_t grow = ((size_t)(b * 4 + tr) << 8) + s0 + ss;
      float4 a = *(const float4*)&x[grow * 512 + k0 + kg * 4];
      int sl = r ^ (4 * (kg ^ tr));       // stays in [tr*64, tr*64+64)
      sA[(4 * kg + 0) * SA_STR + sl] = a.x;
      sA[(4 * kg + 1) * SA_STR + sl] = a.y;
      sA[(4 * kg + 2) * SA_STR + sl] = a.z;
      sA[(4 * kg + 3) * SA_STR + sl] = a.w;
    }
    // stage B: 128 cols x 32 k
#pragma unroll
    for (int j = 0; j < 4; ++j) {
      int c = u + 32 * j;
      float4 wv = *(const float4*)&w1[(size_t)(h0 + c) * 512 + k0 + kg * 4];
      int sl = c ^ (4 * kg);              // stays in [0,128)
      sB[(4 * kg + 0) * SB_STR + sl] = wv.x;
      sB[(4 * kg + 1) * SB_STR + sl] = wv.y;
      sB[(4 * kg + 2) * SB_STR + sl] = wv.z;
      sB[(4 * kg + 3) * SB_STR + sl] = wv.w;
    }
    __syncthreads();

    for (int kk = 0; kk < K1KT; kk += 4) {
      const int aXor = kk ^ tXor;   // = 4*((k>>2) ^ t) for k in [kk,kk+4)
      const int bXor = kk;
#pragma unroll
      for (int k2i = 0; k2i < 4; ++k2i) {
        const int k = kk + k2i;
        const float* aRow = &sA[k * SA_STR];
        const float* bRow = &sB[k * SB_STR];
        float4 a0 = *(const float4*)&aRow[(aBase + 0)  ^ aXor];
        float4 a1 = *(const float4*)&aRow[(aBase + 4)  ^ aXor];
        float4 a2 = *(const float4*)&aRow[(aBase + 8)  ^ aXor];
        float4 a3 = *(const float4*)&aRow[(aBase + 12) ^ aXor];
        float4 b0 = *(const float4*)&bRow[bBase0 ^ bXor];
        float4 b1 = *(const float4*)&bRow[bBase1 ^ bXor];
        float av[16] = {a0.x, a0.y, a0.z, a0.w, a1.x, a1.y, a1.z, a1.w,
                        a2.x, a2.y, a2.z, a2.w, a3.x, a3.y, a3.z, a3.w};
        float bv[8]  = {b0.x, b0.y, b0.z, b0.w, b1.x, b1.y, b1.z, b1.w};
#pragma unroll
        for (int i = 0; i < 16; ++i)
#pragma unroll
          for (int j = 0; j < 8; ++j)
            acc[i][j] = __builtin_fmaf(av[i], bv[j], acc[i][j]);
      }
    }
  }

  // Epilogue: LIF per (s,col) via shfl across the 4 t-owner lanes (t*16+tx).
  unsigned cnt = 0;
#pragma unroll
  for (int i = 0; i < 16; ++i) {
    unsigned short sp[8];
#pragma unroll
    for (int j = 0; j < 8; ++j) {
      float a = acc[i][j];
      float h[4];
#pragma unroll
      for (int tt = 0; tt < 4; ++tt)
        h[tt] = __shfl(a, tt * 16 + tx, 64);
      float vv = 0.0f;
      bool smine = false;
#pragma unroll
      for (int tt = 0; tt < 4; ++tt) {
        vv = __fadd_rn(__fmul_rn(0.95f, vv), h[tt]);   // numpy op-for-op
        bool s = vv > 1.0f;
        smine = (tt == t) ? s : smine;
        vv = s ? 0.0f : vv;
      }
      cnt += smine ? 1u : 0u;
      sp[j] = smine ? (unsigned short)0x3F80 : (unsigned short)0;
    }
    size_t grow = ((size_t)(b * 4 + t) << 8) + s0 + ssg * 16 + i;
    unsigned short* rowp = spikes + grow * 2048 + h0;
    *(ushort4*)&rowp[tx * 4]      = *(const ushort4*)&sp[0];
    *(ushort4*)&rowp[64 + tx * 4] = *(const ushort4*)&sp[4];
  }

  // wave-reduce spike count -> one atomic per wave
#pragma unroll
  for (int off = 32; off; off >>= 1) cnt += __shfl_down(cnt, off);
  if ((tid & 63) == 0) atomicAdd(cnt_out, cnt);
}

// ---------------------------------------------------------------------------
// K2: out = spikes @ (w2_hi + w2_lo)^T via bf16 MFMA, fp32 accum.
// 128x128 tile, BK=64, global_load_lds w=16, XOR swizzle. Grid (128, 4).
// ---------------------------------------------------------------------------
__global__ __launch_bounds__(256, 2) void k2_gemm_mfma(
    const unsigned short* __restrict__ spikes,  // (16384, 2048) bf16
    const unsigned short* __restrict__ w2h,     // (512, 2048) bf16
    const unsigned short* __restrict__ w2l,     // (512, 2048) bf16
    float* __restrict__ out)                    // (16384, 512) fp32
{
  __shared__ alignas(16) short smA [128 * 64];
  __shared__ alignas(16) short smBh[128 * 64];
  __shared__ alignas(16) short smBl[128 * 64];

  const int tid  = threadIdx.x;
  const int lane = tid & 63;
  const int quad = lane >> 4;
  const int l15  = lane & 15;
  const int wv   = tid >> 6;
  const int wm   = wv & 1;
  const int wn   = wv >> 1;

  const size_t r0 = (size_t)blockIdx.x * 128;
  const int    d0 = blockIdx.y * 128;

  int srow[4], sg8[4];
#pragma unroll
  for (int j = 0; j < 4; ++j) {
    int gi  = j * 256 + tid;
    srow[j] = gi >> 3;
    sg8[j]  = ((gi & 7) ^ (srow[j] & 7)) * 8;
  }

  const unsigned short* ab  = spikes + r0 * 2048;
  const unsigned short* bhb = w2h + (size_t)d0 * 2048;
  const unsigned short* blb = w2l + (size_t)d0 * 2048;

  f32x4 acc[4][4] = {};

  for (int k0 = 0; k0 < 2048; k0 += 64) {
    __syncthreads();
#pragma unroll
    for (int j = 0; j < 4; ++j) {
      load_lds16(ab  + (size_t)srow[j] * 2048 + k0 + sg8[j],
                 &smA [(j * 256 + tid) * 8]);
      load_lds16(bhb + (size_t)srow[j] * 2048 + k0 + sg8[j],
                 &smBh[(j * 256 + tid) * 8]);
      load_lds16(blb + (size_t)srow[j] * 2048 + k0 + sg8[j],
                 &smBl[(j * 256 + tid) * 8]);
    }
    __syncthreads();

#pragma unroll
    for (int ks = 0; ks < 2; ++ks) {
      short8 af[4], bh[4], bl[4];
#pragma unroll
      for (int mi = 0; mi < 4; ++mi) {
        int m = wm * 64 + mi * 16 + l15;
        af[mi] = ((const short8*)smA)[m * 8 + ((ks * 4 + quad) ^ (m & 7))];
      }
#pragma unroll
      for (int ni = 0; ni < 4; ++ni) {
        int n = wn * 64 + ni * 16 + l15;
        int sl = n * 8 + ((ks * 4 + quad) ^ (n & 7));
        bh[ni] = ((const short8*)smBh)[sl];
        bl[ni] = ((const short8*)smBl)[sl];
      }
#pragma unroll
      for (int mi = 0; mi < 4; ++mi)
#pragma unroll
        for (int ni = 0; ni < 4; ++ni) {
          acc[mi][ni] = __builtin_amdgcn_mfma_f32_16x16x32_bf16(
              af[mi], bh[ni], acc[mi][ni], 0, 0, 0);
          acc[mi][ni] = __builtin_amdgcn_mfma_f32_16x16x32_bf16(
              af[mi], bl[ni], acc[mi][ni], 0, 0, 0);
        }
    }
  }

  float* ob = out + r0 * 512 + d0;
#pragma unroll
  for (int mi = 0; mi < 4; ++mi)
#pragma unroll
    for (int ni = 0; ni < 4; ++ni)
#pragma unroll
      for (int r = 0; r < 4; ++r) {
        int rr = wm * 64 + mi * 16 + quad * 4 + r;   // C/D: row=quad*4+reg
        int cc = wn * 64 + ni * 16 + l15;            //      col=lane&15
        ob[(size_t)rr * 512 + cc] = acc[mi][ni][r];
      }
}

// ---------------------------------------------------------------------------
// K2 fallback (no extra ws): out = spikes @ w2^T, fp32 VALU. Grid (256, 8).
// ---------------------------------------------------------------------------
#define KT 16
#define PADF 68

__global__ __launch_bounds__(256) void k2_gemm_valu(
    const unsigned short* __restrict__ spikes,
    const float* __restrict__ w2,
    float* __restrict__ out)
{
  __shared__ float sA[KT][PADF];
  __shared__ float sB[KT][PADF];

  const int tid = threadIdx.x;
  const int tx  = tid & 15;
  const int ty  = tid >> 4;
  const int lr  = tid >> 2;
  const int lg  = tid & 3;

  const size_t r0 = (size_t)blockIdx.x * 64;
  const int    d0 = blockIdx.y * 64;

  float acc[4][4];
#pragma unroll
  for (int i = 0; i < 4; ++i)
#pragma unroll
    for (int j = 0; j < 4; ++j) acc[i][j] = 0.0f;

  for (int k0 = 0; k0 < 2048; k0 += KT) {
    __syncthreads();
    ushort4 av = *(const ushort4*)&spikes[(r0 + lr) * 2048 + k0 + lg * 4];
    float4  bv = *(const float4*)&w2[(size_t)(d0 + lr) * 2048 + k0 + lg * 4];
    sA[lg * 4 + 0][lr] = bf2f(av.x); sA[lg * 4 + 1][lr] = bf2f(av.y);
    sA[lg * 4 + 2][lr] = bf2f(av.z); sA[lg * 4 + 3][lr] = bf2f(av.w);
    sB[lg * 4 + 0][lr] = bv.x; sB[lg * 4 + 1][lr] = bv.y;
    sB[lg * 4 + 2][lr] = bv.z; sB[lg * 4 + 3][lr] = bv.w;
    __syncthreads();

#pragma unroll
    for (int k = 0; k < KT; ++k) {
      float4 a4 = *(const float4*)&sA[k][ty * 4];
      float4 b4 = *(const float4*)&sB[k][tx * 4];
      float aa[4] = {a4.x, a4.y, a4.z, a4.w};
      float bb[4] = {b4.x, b4.y, b4.z, b4.w};
#pragma unroll
      for (int i = 0; i < 4; ++i)
#pragma unroll
        for (int j = 0; j < 4; ++j)
          acc[i][j] = __builtin_fmaf(aa[i], bb[j], acc[i][j]);
    }
  }

#pragma unroll
  for (int i = 0; i < 4; ++i) {
    float4 o = make_float4(acc[i][0], acc[i][1], acc[i][2], acc[i][3]);
    *(float4*)&out[(r0 + ty * 4 + i) * 512 + d0 + tx * 4] = o;
  }
}

// ---------------------------------------------------------------------------
// K3: rate = count / 33554432 -> fp32 at d_out[8388608]
// ---------------------------------------------------------------------------
__global__ void k3_rate(const unsigned* __restrict__ cnt, float* __restrict__ dst) {
  dst[0] = (float)((double)(*cnt) / 33554432.0);
}

extern "C" void kernel_launch(void* const* d_in, const int* in_sizes, int n_in,
                              void* d_out, int out_size, void* d_ws, size_t ws_size,
                              hipStream_t stream) {
  const float* x  = (const float*)d_in[0];
  const float* w1 = (const float*)d_in[1];
  const float* w2 = (const float*)d_in[2];
  float* out = (float*)d_out;

  unsigned* cnt = (unsigned*)d_ws;
  unsigned short* spikes = (unsigned short*)((char*)d_ws + 256);
  const size_t SPIKES_B = (size_t)16384 * 2048 * 2;           // 67108864
  unsigned short* w2h = (unsigned short*)((char*)d_ws + 256 + SPIKES_B);
  unsigned short* w2l = w2h + (size_t)512 * 2048;
  const size_t NEED_SPLIT = 256 + SPIKES_B + 2 * (size_t)512 * 2048 * 2;

  hipMemsetAsync(d_ws, 0, 256, stream);  // zero the spike counter

  hipLaunchKernelGGL(k1_gemm_lif, dim3(64, 16), dim3(256), 0, stream,
                     x, w1, spikes, cnt);

  if (ws_size >= NEED_SPLIT) {
    hipLaunchKernelGGL(k0_split, dim3(1024), dim3(256), 0, stream, w2, w2h, w2l);
    hipLaunchKernelGGL(k2_gemm_mfma, dim3(128, 4), dim3(256), 0, stream,
                       spikes, w2h, w2l, out);
  } else {
    hipLaunchKernelGGL(k2_gemm_valu, dim3(256, 8), dim3(256), 0, stream,
                       spikes, w2, out);
  }

  hipLaunchKernelGGL(k3_rate, dim3(1), dim3(1), 0, stream, cnt, out + 8388608);
}